// Round 1
// baseline (266.629 us; speedup 1.0000x reference)
//
#include <hip/hip_runtime.h>
#include <hip/hip_bf16.h>
#include <math.h>

#define BB 8
#define NN 2048
#define DD 1024
#define K2D 2048
#define MTOT (BB * NN)

typedef __attribute__((ext_vector_type(8))) short bf16x8_t;
typedef __attribute__((ext_vector_type(4))) float f32x4_t;

__device__ __forceinline__ unsigned short f2bf(float f) {
  unsigned int u = __float_as_uint(f);
  unsigned int r = (u + 0x7FFFu + ((u >> 16) & 1u)) >> 16;
  return (unsigned short)r;
}

__device__ __forceinline__ void gload_lds16(const void* g, void* lds) {
  __builtin_amdgcn_global_load_lds(
      (const __attribute__((address_space(1))) void*)g,
      (__attribute__((address_space(3))) void*)lds, 16, 0, 0);
}

// K0: W2 [2048,1024] f32 -> W2T [1024,2048] bf16 (W2T[n][k] = W2[k][n])
__global__ void k0_w2t(const float* __restrict__ W2, unsigned short* __restrict__ W2T) {
  __shared__ float tile[32][33];
  const int nb = blockIdx.x * 32;  // col of W2 = row of W2T
  const int kb = blockIdx.y * 32;  // row of W2 = col of W2T
  const int tx = threadIdx.x & 31, ty = threadIdx.x >> 5;  // 32x8
  #pragma unroll
  for (int i = 0; i < 32; i += 8)
    tile[ty + i][tx] = W2[(size_t)(kb + ty + i) * DD + nb + tx];
  __syncthreads();
  #pragma unroll
  for (int i = 0; i < 32; i += 8)
    W2T[(size_t)(nb + ty + i) * K2D + kb + tx] = f2bf(tile[tx][ty + i]);
}

// K1: per-row sumsq -> scale; data f32 -> bf16 into Abuf[:, 0:1024]
__global__ void k1_norm(const float* __restrict__ data, unsigned short* __restrict__ Abuf,
                        float* __restrict__ scale) {
  const int row = blockIdx.x;
  const int t = threadIdx.x;  // 256 threads, 4 floats each
  float4 v = ((const float4*)(data + (size_t)row * DD))[t];
  float ss = v.x * v.x + v.y * v.y + v.z * v.z + v.w * v.w;
  #pragma unroll
  for (int i = 1; i < 64; i <<= 1) ss += __shfl_xor(ss, i);
  __shared__ float red[4];
  if ((t & 63) == 0) red[t >> 6] = ss;
  __syncthreads();
  if (t == 0) {
    float tot = red[0] + red[1] + red[2] + red[3];
    scale[row] = rsqrtf(fmaxf(tot, 1e-12f));
  }
  ushort4 o = make_ushort4(f2bf(v.x), f2bf(v.y), f2bf(v.z), f2bf(v.w));
  *(ushort4*)(&Abuf[(size_t)row * K2D + t * 4]) = o;
}

// K2: per batch, G = X@X^T (X = bf16 data rows), partial[row][ct*2+wc] = sum_cols s[col]*relu(G)
__launch_bounds__(256)
__global__ void k2_sim(const unsigned short* __restrict__ Abuf,
                       const float* __restrict__ scale,
                       float* __restrict__ partial) {
  __shared__ short As_s[128 * 64];
  __shared__ short Bs_s[128 * 64];
  const int t = threadIdx.x;
  const int w = t >> 6, l = t & 63;
  const int wr = w >> 1, wc = w & 1;
  const int b = blockIdx.z, rt = blockIdx.y, ct = blockIdx.x;
  const size_t bbase = (size_t)b * NN * K2D;
  const unsigned short* Ag = Abuf + bbase + (size_t)rt * 128 * K2D;
  const unsigned short* Bg = Abuf + bbase + (size_t)ct * 128 * K2D;
  const int lr = l >> 3;
  const int cg = (l & 7) ^ lr;  // swizzled global 16B-chunk
  f32x4_t acc[4][4] = {};

  for (int ks = 0; ks < DD / 64; ++ks) {
    #pragma unroll
    for (int i = 0; i < 4; ++i) {
      const int rl = i * 32 + w * 8 + lr;
      gload_lds16(Ag + (size_t)rl * K2D + ks * 64 + cg * 8, &As_s[(i * 32 + w * 8) * 64]);
      gload_lds16(Bg + (size_t)rl * K2D + ks * 64 + cg * 8, &Bs_s[(i * 32 + w * 8) * 64]);
    }
    __syncthreads();
    const bf16x8_t* As = (const bf16x8_t*)As_s;
    const bf16x8_t* Bs = (const bf16x8_t*)Bs_s;
    #pragma unroll
    for (int kk = 0; kk < 2; ++kk) {
      const int ci = kk * 4 + (l >> 4);
      bf16x8_t af[4], bq[4];
      #pragma unroll
      for (int m = 0; m < 4; ++m) {
        const int r = wr * 64 + m * 16 + (l & 15);
        af[m] = As[r * 8 + (ci ^ (r & 7))];
      }
      #pragma unroll
      for (int n = 0; n < 4; ++n) {
        const int r = wc * 64 + n * 16 + (l & 15);
        bq[n] = Bs[r * 8 + (ci ^ (r & 7))];
      }
      #pragma unroll
      for (int m = 0; m < 4; ++m)
        #pragma unroll
        for (int n = 0; n < 4; ++n)
          acc[m][n] = __builtin_amdgcn_mfma_f32_16x16x32_bf16(af[m], bq[n], acc[m][n], 0, 0, 0);
    }
    __syncthreads();
  }

  const float* sb = scale + (size_t)b * NN;
  float scol[4];
  #pragma unroll
  for (int n = 0; n < 4; ++n)
    scol[n] = sb[ct * 128 + wc * 64 + n * 16 + (l & 15)];
  #pragma unroll
  for (int m = 0; m < 4; ++m) {
    #pragma unroll
    for (int r = 0; r < 4; ++r) {
      float x = 0.f;
      #pragma unroll
      for (int n = 0; n < 4; ++n)
        x += scol[n] * fmaxf(acc[m][n][r], 0.f);
      #pragma unroll
      for (int off = 1; off < 16; off <<= 1)
        x += __shfl_xor(x, off);
      if ((l & 15) == 0) {
        const int row = rt * 128 + wr * 64 + m * 16 + (l >> 4) * 4 + r;
        partial[((size_t)(b * NN + row)) * 32 + ct * 2 + wc] = x;
      }
    }
  }
}

// K3: counter = s[row]*sum(partials); Abuf[:,1024+d] = bf16(softplus(c*W1[d]+b1[d]))
__global__ void k3_expand(const float* __restrict__ partial, const float* __restrict__ scale,
                          const float* __restrict__ W1, const float* __restrict__ b1,
                          unsigned short* __restrict__ Abuf) {
  const int row = blockIdx.x;
  const int t = threadIdx.x;  // 256
  const float* pr = partial + (size_t)row * 32;
  float c = 0.f;
  #pragma unroll
  for (int i = 0; i < 32; ++i) c += pr[i];
  c *= scale[row];
  float4 wv = ((const float4*)W1)[t];
  float4 bv = ((const float4*)b1)[t];
  float xs[4] = {c * wv.x + bv.x, c * wv.y + bv.y, c * wv.z + bv.z, c * wv.w + bv.w};
  unsigned short o[4];
  #pragma unroll
  for (int j = 0; j < 4; ++j) {
    float x = xs[j];
    float sp = (x > 20.f) ? x : log1pf(expf(x));
    o[j] = f2bf(sp);
  }
  *(ushort4*)(&Abuf[(size_t)row * K2D + DD + t * 4]) = *(ushort4*)o;
}

// K4: out [16384,1024] f32 = Abuf [16384,2048] bf16 @ W2T^T (W2T [1024,2048] bf16)
__launch_bounds__(256)
__global__ void k4_out(const unsigned short* __restrict__ Abuf,
                       const unsigned short* __restrict__ W2T,
                       float* __restrict__ out) {
  __shared__ short As_s[128 * 64];
  __shared__ short Bs_s[128 * 64];
  const int t = threadIdx.x;
  const int w = t >> 6, l = t & 63;
  const int wr = w >> 1, wc = w & 1;
  const int ct = blockIdx.x;     // 0..7 over N=1024
  const int rtile = blockIdx.y;  // 0..127 over M=16384
  const unsigned short* Ag = Abuf + (size_t)rtile * 128 * K2D;
  const unsigned short* Bg = W2T + (size_t)ct * 128 * K2D;
  const int lr = l >> 3;
  const int cg = (l & 7) ^ lr;
  f32x4_t acc[4][4] = {};

  for (int ks = 0; ks < K2D / 64; ++ks) {
    #pragma unroll
    for (int i = 0; i < 4; ++i) {
      const int rl = i * 32 + w * 8 + lr;
      gload_lds16(Ag + (size_t)rl * K2D + ks * 64 + cg * 8, &As_s[(i * 32 + w * 8) * 64]);
      gload_lds16(Bg + (size_t)rl * K2D + ks * 64 + cg * 8, &Bs_s[(i * 32 + w * 8) * 64]);
    }
    __syncthreads();
    const bf16x8_t* As = (const bf16x8_t*)As_s;
    const bf16x8_t* Bs = (const bf16x8_t*)Bs_s;
    #pragma unroll
    for (int kk = 0; kk < 2; ++kk) {
      const int ci = kk * 4 + (l >> 4);
      bf16x8_t af[4], bq[4];
      #pragma unroll
      for (int m = 0; m < 4; ++m) {
        const int r = wr * 64 + m * 16 + (l & 15);
        af[m] = As[r * 8 + (ci ^ (r & 7))];
      }
      #pragma unroll
      for (int n = 0; n < 4; ++n) {
        const int r = wc * 64 + n * 16 + (l & 15);
        bq[n] = Bs[r * 8 + (ci ^ (r & 7))];
      }
      #pragma unroll
      for (int m = 0; m < 4; ++m)
        #pragma unroll
        for (int n = 0; n < 4; ++n)
          acc[m][n] = __builtin_amdgcn_mfma_f32_16x16x32_bf16(af[m], bq[n], acc[m][n], 0, 0, 0);
    }
    __syncthreads();
  }

  #pragma unroll
  for (int m = 0; m < 4; ++m)
    #pragma unroll
    for (int n = 0; n < 4; ++n)
      #pragma unroll
      for (int r = 0; r < 4; ++r) {
        const int row = rtile * 128 + wr * 64 + m * 16 + (l >> 4) * 4 + r;
        const int col = ct * 128 + wc * 64 + n * 16 + (l & 15);
        out[(size_t)row * DD + col] = acc[m][n][r];
      }
}

extern "C" void kernel_launch(void* const* d_in, const int* in_sizes, int n_in,
                              void* d_out, int out_size, void* d_ws, size_t ws_size,
                              hipStream_t stream) {
  const float* data = (const float*)d_in[0];
  const float* W1 = (const float*)d_in[1];
  const float* b1 = (const float*)d_in[2];
  const float* W2 = (const float*)d_in[3];
  float* out = (float*)d_out;

  char* ws = (char*)d_ws;
  unsigned short* Abuf = (unsigned short*)ws;                       // 16384*2048*2 = 67108864 B
  unsigned short* W2T = (unsigned short*)(ws + 67108864);           // 1024*2048*2  =  4194304 B
  float* partial = (float*)(ws + 67108864 + 4194304);               // 16384*32*4   =  2097152 B
  float* scale = (float*)(ws + 67108864 + 4194304 + 2097152);       // 16384*4      =    65536 B

  hipLaunchKernelGGL(k0_w2t, dim3(DD / 32, K2D / 32), dim3(256), 0, stream, W2, W2T);
  hipLaunchKernelGGL(k1_norm, dim3(MTOT), dim3(256), 0, stream, data, Abuf, scale);
  hipLaunchKernelGGL(k2_sim, dim3(NN / 128, NN / 128, BB), dim3(256), 0, stream,
                     Abuf, scale, partial);
  hipLaunchKernelGGL(k3_expand, dim3(MTOT), dim3(256), 0, stream, partial, scale, W1, b1, Abuf);
  hipLaunchKernelGGL(k4_out, dim3(DD / 128, MTOT / 128), dim3(256), 0, stream, Abuf, W2T, out);
}

// Round 3
// 197.914 us; speedup vs baseline: 1.3472x; 1.3472x over previous
//
#include <hip/hip_runtime.h>
#include <hip/hip_bf16.h>
#include <math.h>

#define BB 8
#define NN 2048
#define DD 1024
#define K2D 2048
#define MTOT (BB * NN)
#define NT (NN / 128)            // 16 row/col tiles per batch
#define NTRI (NT * (NT + 1) / 2) // 136 triangular tiles

typedef __attribute__((ext_vector_type(8))) short bf16x8_t;
typedef __attribute__((ext_vector_type(4))) float f32x4_t;

__device__ __forceinline__ unsigned short f2bf(float f) {
  unsigned int u = __float_as_uint(f);
  unsigned int r = (u + 0x7FFFu + ((u >> 16) & 1u)) >> 16;
  return (unsigned short)r;
}

__device__ __forceinline__ void gload_lds16(const void* g, void* lds) {
  __builtin_amdgcn_global_load_lds(
      (const __attribute__((address_space(1))) void*)g,
      (__attribute__((address_space(3))) void*)lds, 16, 0, 0);
}

// K0: W2 [2048,1024] f32 -> W2T [1024,2048] bf16 (W2T[n][k] = W2[k][n])
__global__ void k0_w2t(const float* __restrict__ W2, unsigned short* __restrict__ W2T) {
  __shared__ float tile[32][33];
  const int nb = blockIdx.x * 32;
  const int kb = blockIdx.y * 32;
  const int tx = threadIdx.x & 31, ty = threadIdx.x >> 5;
  #pragma unroll
  for (int i = 0; i < 32; i += 8)
    tile[ty + i][tx] = W2[(size_t)(kb + ty + i) * DD + nb + tx];
  __syncthreads();
  #pragma unroll
  for (int i = 0; i < 32; i += 8)
    W2T[(size_t)(nb + ty + i) * K2D + kb + tx] = f2bf(tile[tx][ty + i]);
}

// K1: per-row sumsq -> scale; data f32 -> bf16 into Abuf[:, 0:1024]
__global__ void k1_norm(const float* __restrict__ data, unsigned short* __restrict__ Abuf,
                        float* __restrict__ scale) {
  const int row = blockIdx.x;
  const int t = threadIdx.x;
  float4 v = ((const float4*)(data + (size_t)row * DD))[t];
  float ss = v.x * v.x + v.y * v.y + v.z * v.z + v.w * v.w;
  #pragma unroll
  for (int i = 1; i < 64; i <<= 1) ss += __shfl_xor(ss, i);
  __shared__ float red[4];
  if ((t & 63) == 0) red[t >> 6] = ss;
  __syncthreads();
  if (t == 0) {
    float tot = red[0] + red[1] + red[2] + red[3];
    scale[row] = rsqrtf(fmaxf(tot, 1e-12f));
  }
  ushort4 o = make_ushort4(f2bf(v.x), f2bf(v.y), f2bf(v.z), f2bf(v.w));
  *(ushort4*)(&Abuf[(size_t)row * K2D + t * 4]) = o;
}

// K2: triangular blocks rt<=ct of G = X@X^T per batch.
// Off-diagonal blocks emit BOTH row-side and col-side weighted partials
// (relu(G) symmetric). Diagonal blocks emit row-side only.
// partial[row][slot]: row-side -> slot ct*2+wc ; col-side -> slot rt*2+wr.
__launch_bounds__(256)
__global__ void k2_sim(const unsigned short* __restrict__ Abuf,
                       const float* __restrict__ scale,
                       float* __restrict__ partial) {
  __shared__ short As_s[128 * 64];
  __shared__ short Bs_s[128 * 64];
  const int t = threadIdx.x;
  const int w = t >> 6, l = t & 63;
  const int wr = w >> 1, wc = w & 1;

  // XCD-aware: each XCD owns a contiguous chunk of logical ids (nwg=1088, %8==0)
  const int nwg = BB * NTRI;
  const int logical = (blockIdx.x % 8) * (nwg / 8) + blockIdx.x / 8;
  const int b = logical / NTRI;
  int p = logical % NTRI;
  int rt = 0;
  while (p >= NT - rt) { p -= NT - rt; ++rt; }
  const int ct = rt + p;

  const size_t bbase = (size_t)b * NN * K2D;
  const unsigned short* Ag = Abuf + bbase + (size_t)rt * 128 * K2D;
  const unsigned short* Bg = Abuf + bbase + (size_t)ct * 128 * K2D;
  const int lr = l >> 3;
  const int cg = (l & 7) ^ lr;  // swizzled global 16B-chunk
  f32x4_t acc[4][4] = {};

  for (int ks = 0; ks < DD / 64; ++ks) {
    #pragma unroll
    for (int i = 0; i < 4; ++i) {
      const int rl = i * 32 + w * 8 + lr;
      gload_lds16(Ag + (size_t)rl * K2D + ks * 64 + cg * 8, &As_s[(i * 32 + w * 8) * 64]);
      gload_lds16(Bg + (size_t)rl * K2D + ks * 64 + cg * 8, &Bs_s[(i * 32 + w * 8) * 64]);
    }
    __syncthreads();
    const bf16x8_t* As = (const bf16x8_t*)As_s;
    const bf16x8_t* Bs = (const bf16x8_t*)Bs_s;
    #pragma unroll
    for (int kk = 0; kk < 2; ++kk) {
      const int ci = kk * 4 + (l >> 4);
      bf16x8_t af[4], bq[4];
      #pragma unroll
      for (int m = 0; m < 4; ++m) {
        const int r = wr * 64 + m * 16 + (l & 15);
        af[m] = As[r * 8 + (ci ^ (r & 7))];
      }
      #pragma unroll
      for (int n = 0; n < 4; ++n) {
        const int r = wc * 64 + n * 16 + (l & 15);
        bq[n] = Bs[r * 8 + (ci ^ (r & 7))];
      }
      #pragma unroll
      for (int m = 0; m < 4; ++m)
        #pragma unroll
        for (int n = 0; n < 4; ++n)
          acc[m][n] = __builtin_amdgcn_mfma_f32_16x16x32_bf16(af[m], bq[n], acc[m][n], 0, 0, 0);
    }
    __syncthreads();
  }

  const float* sb = scale + (size_t)b * NN;

  // row-side: for rows of rt tile, sum over this block's cols, weight s[col]
  {
    float scol[4];
    #pragma unroll
    for (int n = 0; n < 4; ++n)
      scol[n] = sb[ct * 128 + wc * 64 + n * 16 + (l & 15)];
    #pragma unroll
    for (int m = 0; m < 4; ++m) {
      #pragma unroll
      for (int r = 0; r < 4; ++r) {
        float x = 0.f;
        #pragma unroll
        for (int n = 0; n < 4; ++n)
          x += scol[n] * fmaxf(acc[m][n][r], 0.f);
        #pragma unroll
        for (int off = 1; off < 16; off <<= 1)
          x += __shfl_xor(x, off);
        if ((l & 15) == 0) {
          const int row = rt * 128 + wr * 64 + m * 16 + (l >> 4) * 4 + r;
          partial[((size_t)(b * NN + row)) * 32 + ct * 2 + wc] = x;
        }
      }
    }
  }

  // col-side (off-diagonal only): for rows of ct tile (= this block's cols),
  // sum over this block's rows, weight s[row]
  if (rt != ct) {
    float srow[4][4];
    #pragma unroll
    for (int m = 0; m < 4; ++m)
      #pragma unroll
      for (int r = 0; r < 4; ++r)
        srow[m][r] = sb[rt * 128 + wr * 64 + m * 16 + (l >> 4) * 4 + r];
    #pragma unroll
    for (int n = 0; n < 4; ++n) {
      float y = 0.f;
      #pragma unroll
      for (int m = 0; m < 4; ++m)
        #pragma unroll
        for (int r = 0; r < 4; ++r)
          y += srow[m][r] * fmaxf(acc[m][n][r], 0.f);
      y += __shfl_xor(y, 16);
      y += __shfl_xor(y, 32);
      if (l < 16) {
        const int crow = ct * 128 + wc * 64 + n * 16 + l;
        partial[((size_t)(b * NN + crow)) * 32 + rt * 2 + wr] = y;
      }
    }
  }
}

// K3: counter = s[row]*sum(partials); Abuf[:,1024+d] = bf16(softplus(c*W1[d]+b1[d]))
__global__ void k3_expand(const float* __restrict__ partial, const float* __restrict__ scale,
                          const float* __restrict__ W1, const float* __restrict__ b1,
                          unsigned short* __restrict__ Abuf) {
  const int row = blockIdx.x;
  const int t = threadIdx.x;
  const float* pr = partial + (size_t)row * 32;
  float c = 0.f;
  #pragma unroll
  for (int i = 0; i < 32; ++i) c += pr[i];
  c *= scale[row];
  float4 wv = ((const float4*)W1)[t];
  float4 bv = ((const float4*)b1)[t];
  float xs[4] = {c * wv.x + bv.x, c * wv.y + bv.y, c * wv.z + bv.z, c * wv.w + bv.w};
  unsigned short o[4];
  #pragma unroll
  for (int j = 0; j < 4; ++j) {
    float x = xs[j];
    float sp = (x > 20.f) ? x : log1pf(expf(x));
    o[j] = f2bf(sp);
  }
  *(ushort4*)(&Abuf[(size_t)row * K2D + DD + t * 4]) = *(ushort4*)o;
}

// K4: out [16384,1024] f32 = Abuf [16384,2048] bf16 @ W2T^T (W2T [1024,2048] bf16)
// 1D grid of 1024 blocks; logical = rtile*8+ct, XCD-chunk swizzled.
__launch_bounds__(256)
__global__ void k4_out(const unsigned short* __restrict__ Abuf,
                       const unsigned short* __restrict__ W2T,
                       float* __restrict__ out) {
  __shared__ short As_s[128 * 64];
  __shared__ short Bs_s[128 * 64];
  const int t = threadIdx.x;
  const int w = t >> 6, l = t & 63;
  const int wr = w >> 1, wc = w & 1;

  // XCD-aware: each XCD gets 16 consecutive rtiles x all 8 cts (nwg=1024, %8==0)
  const int logical = (blockIdx.x % 8) * 128 + blockIdx.x / 8;
  const int rtile = logical >> 3;
  const int ct = logical & 7;

  const unsigned short* Ag = Abuf + (size_t)rtile * 128 * K2D;
  const unsigned short* Bg = W2T + (size_t)ct * 128 * K2D;
  const int lr = l >> 3;
  const int cg = (l & 7) ^ lr;
  f32x4_t acc[4][4] = {};

  for (int ks = 0; ks < K2D / 64; ++ks) {
    #pragma unroll
    for (int i = 0; i < 4; ++i) {
      const int rl = i * 32 + w * 8 + lr;
      gload_lds16(Ag + (size_t)rl * K2D + ks * 64 + cg * 8, &As_s[(i * 32 + w * 8) * 64]);
      gload_lds16(Bg + (size_t)rl * K2D + ks * 64 + cg * 8, &Bs_s[(i * 32 + w * 8) * 64]);
    }
    __syncthreads();
    const bf16x8_t* As = (const bf16x8_t*)As_s;
    const bf16x8_t* Bs = (const bf16x8_t*)Bs_s;
    #pragma unroll
    for (int kk = 0; kk < 2; ++kk) {
      const int ci = kk * 4 + (l >> 4);
      bf16x8_t af[4], bq[4];
      #pragma unroll
      for (int m = 0; m < 4; ++m) {
        const int r = wr * 64 + m * 16 + (l & 15);
        af[m] = As[r * 8 + (ci ^ (r & 7))];
      }
      #pragma unroll
      for (int n = 0; n < 4; ++n) {
        const int r = wc * 64 + n * 16 + (l & 15);
        bq[n] = Bs[r * 8 + (ci ^ (r & 7))];
      }
      #pragma unroll
      for (int m = 0; m < 4; ++m)
        #pragma unroll
        for (int n = 0; n < 4; ++n)
          acc[m][n] = __builtin_amdgcn_mfma_f32_16x16x32_bf16(af[m], bq[n], acc[m][n], 0, 0, 0);
    }
    __syncthreads();
  }

  #pragma unroll
  for (int m = 0; m < 4; ++m)
    #pragma unroll
    for (int n = 0; n < 4; ++n)
      #pragma unroll
      for (int r = 0; r < 4; ++r) {
        const int row = rtile * 128 + wr * 64 + m * 16 + (l >> 4) * 4 + r;
        const int col = ct * 128 + wc * 64 + n * 16 + (l & 15);
        out[(size_t)row * DD + col] = acc[m][n][r];
      }
}

extern "C" void kernel_launch(void* const* d_in, const int* in_sizes, int n_in,
                              void* d_out, int out_size, void* d_ws, size_t ws_size,
                              hipStream_t stream) {
  const float* data = (const float*)d_in[0];
  const float* W1 = (const float*)d_in[1];
  const float* b1 = (const float*)d_in[2];
  const float* W2 = (const float*)d_in[3];
  float* out = (float*)d_out;

  char* ws = (char*)d_ws;
  unsigned short* Abuf = (unsigned short*)ws;                       // 67108864 B
  unsigned short* W2T = (unsigned short*)(ws + 67108864);           //  4194304 B
  float* partial = (float*)(ws + 67108864 + 4194304);               //  2097152 B
  float* scale = (float*)(ws + 67108864 + 4194304 + 2097152);       //    65536 B

  hipLaunchKernelGGL(k0_w2t, dim3(DD / 32, K2D / 32), dim3(256), 0, stream, W2, W2T);
  hipLaunchKernelGGL(k1_norm, dim3(MTOT), dim3(256), 0, stream, data, Abuf, scale);
  hipLaunchKernelGGL(k2_sim, dim3(BB * NTRI), dim3(256), 0, stream, Abuf, scale, partial);
  hipLaunchKernelGGL(k3_expand, dim3(MTOT), dim3(256), 0, stream, partial, scale, W1, b1, Abuf);
  hipLaunchKernelGGL(k4_out, dim3(MTOT / 128 * (DD / 128)), dim3(256), 0, stream, Abuf, W2T, out);
}

// Round 4
// 180.651 us; speedup vs baseline: 1.4759x; 1.0956x over previous
//
#include <hip/hip_runtime.h>
#include <hip/hip_bf16.h>
#include <math.h>

#define BB 8
#define NN 2048
#define DD 1024
#define MTOT (BB * NN)
#define NT (NN / 128)            // 16 row/col tiles per batch
#define NTRI (NT * (NT + 1) / 2) // 136 triangular tiles
#define NJ 8                     // interpolation nodes

typedef __attribute__((ext_vector_type(8))) short bf16x8_t;
typedef __attribute__((ext_vector_type(4))) float f32x4_t;

__device__ __forceinline__ unsigned short f2bf(float f) {
  unsigned int u = __float_as_uint(f);
  unsigned int r = (u + 0x7FFFu + ((u >> 16) & 1u)) >> 16;
  return (unsigned short)r;
}

__device__ __forceinline__ void gload_lds16(const void* g, void* lds) {
  __builtin_amdgcn_global_load_lds(
      (const __attribute__((address_space(1))) void*)g,
      (__attribute__((address_space(3))) void*)lds, 16, 0, 0);
}

__device__ __forceinline__ float softplusf(float x) {
  return (x > 20.f) ? x : log1pf(expf(x));
}

// K0: W2 top half [1024,1024] f32 -> W2T [1024,1024] bf16 (W2T[n][k] = W2[k][n])
__global__ void k0_w2t(const float* __restrict__ W2, unsigned short* __restrict__ W2T) {
  __shared__ float tile[32][33];
  const int nb = blockIdx.x * 32;
  const int kb = blockIdx.y * 32;
  const int tx = threadIdx.x & 31, ty = threadIdx.x >> 5;
  #pragma unroll
  for (int i = 0; i < 32; i += 8)
    tile[ty + i][tx] = W2[(size_t)(kb + ty + i) * DD + nb + tx];
  __syncthreads();
  #pragma unroll
  for (int i = 0; i < 32; i += 8)
    W2T[(size_t)(nb + ty + i) * DD + kb + tx] = f2bf(tile[tx][ty + i]);
}

// K1: per-row sumsq -> scale; data f32 -> bf16 into Abuf [16384,1024]
__global__ void k1_norm(const float* __restrict__ data, unsigned short* __restrict__ Abuf,
                        float* __restrict__ scale) {
  const int row = blockIdx.x;
  const int t = threadIdx.x;
  float4 v = ((const float4*)(data + (size_t)row * DD))[t];
  float ss = v.x * v.x + v.y * v.y + v.z * v.z + v.w * v.w;
  #pragma unroll
  for (int i = 1; i < 64; i <<= 1) ss += __shfl_xor(ss, i);
  __shared__ float red[4];
  if ((t & 63) == 0) red[t >> 6] = ss;
  __syncthreads();
  if (t == 0) {
    float tot = red[0] + red[1] + red[2] + red[3];
    scale[row] = rsqrtf(fmaxf(tot, 1e-12f));
  }
  ushort4 o = make_ushort4(f2bf(v.x), f2bf(v.y), f2bf(v.z), f2bf(v.w));
  *(ushort4*)(&Abuf[(size_t)row * DD + t * 4]) = o;
}

// K2: triangular blocks rt<=ct of G = X@X^T per batch (X = bf16 data rows).
// Off-diagonal blocks emit row-side AND col-side weighted partials (relu(G) symmetric).
// partial[row][slot]: row-side -> slot ct*2+wc ; col-side -> slot rt*2+wr.
__launch_bounds__(256)
__global__ void k2_sim(const unsigned short* __restrict__ Abuf,
                       const float* __restrict__ scale,
                       float* __restrict__ partial) {
  __shared__ short As_s[128 * 64];
  __shared__ short Bs_s[128 * 64];
  const int t = threadIdx.x;
  const int w = t >> 6, l = t & 63;
  const int wr = w >> 1, wc = w & 1;

  const int nwg = BB * NTRI;  // 1088, %8==0
  const int logical = (blockIdx.x % 8) * (nwg / 8) + blockIdx.x / 8;
  const int b = logical / NTRI;
  int p = logical % NTRI;
  int rt = 0;
  while (p >= NT - rt) { p -= NT - rt; ++rt; }
  const int ct = rt + p;

  const size_t bbase = (size_t)b * NN * DD;
  const unsigned short* Ag = Abuf + bbase + (size_t)rt * 128 * DD;
  const unsigned short* Bg = Abuf + bbase + (size_t)ct * 128 * DD;
  const int lr = l >> 3;
  const int cg = (l & 7) ^ lr;  // swizzled global 16B-chunk
  f32x4_t acc[4][4] = {};

  for (int ks = 0; ks < DD / 64; ++ks) {
    #pragma unroll
    for (int i = 0; i < 4; ++i) {
      const int rl = i * 32 + w * 8 + lr;
      gload_lds16(Ag + (size_t)rl * DD + ks * 64 + cg * 8, &As_s[(i * 32 + w * 8) * 64]);
      gload_lds16(Bg + (size_t)rl * DD + ks * 64 + cg * 8, &Bs_s[(i * 32 + w * 8) * 64]);
    }
    __syncthreads();
    const bf16x8_t* As = (const bf16x8_t*)As_s;
    const bf16x8_t* Bs = (const bf16x8_t*)Bs_s;
    #pragma unroll
    for (int kk = 0; kk < 2; ++kk) {
      const int ci = kk * 4 + (l >> 4);
      bf16x8_t af[4], bq[4];
      #pragma unroll
      for (int m = 0; m < 4; ++m) {
        const int r = wr * 64 + m * 16 + (l & 15);
        af[m] = As[r * 8 + (ci ^ (r & 7))];
      }
      #pragma unroll
      for (int n = 0; n < 4; ++n) {
        const int r = wc * 64 + n * 16 + (l & 15);
        bq[n] = Bs[r * 8 + (ci ^ (r & 7))];
      }
      #pragma unroll
      for (int m = 0; m < 4; ++m)
        #pragma unroll
        for (int n = 0; n < 4; ++n)
          acc[m][n] = __builtin_amdgcn_mfma_f32_16x16x32_bf16(af[m], bq[n], acc[m][n], 0, 0, 0);
    }
    __syncthreads();
  }

  const float* sb = scale + (size_t)b * NN;

  {  // row-side
    float scol[4];
    #pragma unroll
    for (int n = 0; n < 4; ++n)
      scol[n] = sb[ct * 128 + wc * 64 + n * 16 + (l & 15)];
    #pragma unroll
    for (int m = 0; m < 4; ++m) {
      #pragma unroll
      for (int r = 0; r < 4; ++r) {
        float x = 0.f;
        #pragma unroll
        for (int n = 0; n < 4; ++n)
          x += scol[n] * fmaxf(acc[m][n][r], 0.f);
        #pragma unroll
        for (int off = 1; off < 16; off <<= 1)
          x += __shfl_xor(x, off);
        if ((l & 15) == 0) {
          const int row = rt * 128 + wr * 64 + m * 16 + (l >> 4) * 4 + r;
          partial[((size_t)(b * NN + row)) * 32 + ct * 2 + wc] = x;
        }
      }
    }
  }

  if (rt != ct) {  // col-side
    float srow[4][4];
    #pragma unroll
    for (int m = 0; m < 4; ++m)
      #pragma unroll
      for (int r = 0; r < 4; ++r)
        srow[m][r] = sb[rt * 128 + wr * 64 + m * 16 + (l >> 4) * 4 + r];
    #pragma unroll
    for (int n = 0; n < 4; ++n) {
      float y = 0.f;
      #pragma unroll
      for (int m = 0; m < 4; ++m)
        #pragma unroll
        for (int r = 0; r < 4; ++r)
          y += srow[m][r] * fmaxf(acc[m][n][r], 0.f);
      y += __shfl_xor(y, 16);
      y += __shfl_xor(y, 32);
      if (l < 16) {
        const int crow = ct * 128 + wc * 64 + n * 16 + l;
        partial[((size_t)(b * NN + crow)) * 32 + rt * 2 + wr] = y;
      }
    }
  }
}

// K3a: c[row] = scale[row]*sum(partial[row][0..32)); per-block min/max -> mm[64][2]
__global__ void k3a_counter(const float* __restrict__ partial, const float* __restrict__ scale,
                            float* __restrict__ cbuf, float* __restrict__ mm) {
  const int row = blockIdx.x * 256 + threadIdx.x;
  const float4* pr = (const float4*)(partial + (size_t)row * 32);
  float c = 0.f;
  #pragma unroll
  for (int i = 0; i < 8; ++i) { float4 v = pr[i]; c += v.x + v.y + v.z + v.w; }
  c *= scale[row];
  cbuf[row] = c;
  float mn = c, mx = c;
  #pragma unroll
  for (int i = 1; i < 64; i <<= 1) {
    mn = fminf(mn, __shfl_xor(mn, i));
    mx = fmaxf(mx, __shfl_xor(mx, i));
  }
  __shared__ float smn[4], smx[4];
  if ((threadIdx.x & 63) == 0) { smn[threadIdx.x >> 6] = mn; smx[threadIdx.x >> 6] = mx; }
  __syncthreads();
  if (threadIdx.x == 0) {
    mn = fminf(fminf(smn[0], smn[1]), fminf(smn[2], smn[3]));
    mx = fmaxf(fmaxf(smx[0], smx[1]), fmaxf(smx[2], smx[3]));
    mm[blockIdx.x * 2] = mn;
    mm[blockIdx.x * 2 + 1] = mx;
  }
}

// K3b: reduce min/max over 64 blocks; compute 8 Chebyshev nodes + barycentric invD
__global__ void k3b_nodes(const float* __restrict__ mm, float* __restrict__ nd) {
  const int t = threadIdx.x;  // 64
  float mn = mm[t * 2], mx = mm[t * 2 + 1];
  #pragma unroll
  for (int i = 1; i < 64; i <<= 1) {
    mn = fminf(mn, __shfl_xor(mn, i));
    mx = fmaxf(mx, __shfl_xor(mx, i));
  }
  if (t == 0) {
    float mid = 0.5f * (mn + mx);
    float rad = 0.5f * (mx - mn);
    rad = fmaxf(rad, fmaxf(1e-3f, 1e-3f * fabsf(mid)));
    float c[NJ];
    #pragma unroll
    for (int j = 0; j < NJ; ++j)
      c[j] = mid + rad * cosf(3.14159265358979f * (2 * j + 1) / (2.0f * NJ));
    #pragma unroll
    for (int j = 0; j < NJ; ++j) nd[j] = c[j];
    #pragma unroll
    for (int j = 0; j < NJ; ++j) {
      float d = 1.f;
      #pragma unroll
      for (int i = 0; i < NJ; ++i)
        if (i != j) d *= (c[j] - c[i]);
      nd[NJ + j] = 1.f / d;
    }
  }
}

// K3c: S[j][d] = softplus(c_j*W1[d] + b1[d])
__global__ void k3c_softS(const float* __restrict__ nd, const float* __restrict__ W1,
                          const float* __restrict__ b1, float* __restrict__ S) {
  const int gid = blockIdx.x * 256 + threadIdx.x;  // 8192
  const int j = gid >> 10, d = gid & 1023;
  S[gid] = softplusf(nd[j] * W1[d] + b1[d]);
}

// K3d: Fpart[s][j][n] = sum_{d in slice s} S[j][d]*W2[(1024+d)][n]  (64 slices of 16)
__global__ void k3d_Fpart(const float* __restrict__ S, const float* __restrict__ W2,
                          float* __restrict__ Fpart) {
  const int s = blockIdx.x;   // 64
  const int t = threadIdx.x;  // 256 -> float4 over n
  float4 acc[NJ] = {};
  for (int dd = 0; dd < 16; ++dd) {
    const int d = s * 16 + dd;
    float4 wv = ((const float4*)(W2 + (size_t)(DD + d) * DD))[t];
    #pragma unroll
    for (int j = 0; j < NJ; ++j) {
      float sv = S[j * DD + d];
      acc[j].x += sv * wv.x; acc[j].y += sv * wv.y;
      acc[j].z += sv * wv.z; acc[j].w += sv * wv.w;
    }
  }
  #pragma unroll
  for (int j = 0; j < NJ; ++j)
    ((float4*)(Fpart + ((size_t)s * NJ + j) * DD))[t] = acc[j];
}

// K3e: F[j][n] = sum_s Fpart[s][j][n]
__global__ void k3e_Fred(const float* __restrict__ Fpart, float* __restrict__ F) {
  const int gid = blockIdx.x * 256 + threadIdx.x;  // 8192
  float a = 0.f;
  for (int s = 0; s < 64; ++s) a += Fpart[((size_t)s * NJ) * DD + gid];
  F[gid] = a;
}

// K4: out[16384,1024] f32 = Abuf[16384,1024]bf16 @ W2T^T  +  L(c[row]) @ F  (rank-8)
__launch_bounds__(256)
__global__ void k4_out(const unsigned short* __restrict__ Abuf,
                       const unsigned short* __restrict__ W2T,
                       const float* __restrict__ cbuf,
                       const float* __restrict__ nd,
                       const float* __restrict__ F,
                       float* __restrict__ out) {
  __shared__ short As_s[128 * 64];
  __shared__ short Bs_s[128 * 64];
  __shared__ float Fsh[NJ * 128];
  __shared__ float Lsh[128 * NJ];
  const int t = threadIdx.x;
  const int w = t >> 6, l = t & 63;
  const int wr = w >> 1, wc = w & 1;

  // XCD-aware: each XCD gets 16 consecutive rtiles x all 8 cts (nwg=1024)
  const int logical = (blockIdx.x % 8) * 128 + blockIdx.x / 8;
  const int rtile = logical >> 3;
  const int ct = logical & 7;

  const unsigned short* Ag = Abuf + (size_t)rtile * 128 * DD;
  const unsigned short* Bg = W2T + (size_t)ct * 128 * DD;
  const int lr = l >> 3;
  const int cg = (l & 7) ^ lr;
  f32x4_t acc[4][4] = {};

  // stage F slice + barycentric L while the K-loop's first barrier covers us
  {
    #pragma unroll
    for (int q = 0; q < 4; ++q) {
      const int idx = t + q * 256;  // 1024 = 8x128
      const int j = idx >> 7, n = idx & 127;
      Fsh[j * 128 + n] = F[j * DD + ct * 128 + n];
    }
    if (t < 128) {
      const float c = cbuf[rtile * 128 + t];
      #pragma unroll
      for (int j = 0; j < NJ; ++j) {
        float prod = nd[NJ + j];
        #pragma unroll
        for (int i = 0; i < NJ; ++i)
          if (i != j) prod *= (c - nd[i]);
        Lsh[t * NJ + j] = prod;
      }
    }
  }

  for (int ks = 0; ks < DD / 64; ++ks) {
    #pragma unroll
    for (int i = 0; i < 4; ++i) {
      const int rl = i * 32 + w * 8 + lr;
      gload_lds16(Ag + (size_t)rl * DD + ks * 64 + cg * 8, &As_s[(i * 32 + w * 8) * 64]);
      gload_lds16(Bg + (size_t)rl * DD + ks * 64 + cg * 8, &Bs_s[(i * 32 + w * 8) * 64]);
    }
    __syncthreads();
    const bf16x8_t* As = (const bf16x8_t*)As_s;
    const bf16x8_t* Bs = (const bf16x8_t*)Bs_s;
    #pragma unroll
    for (int kk = 0; kk < 2; ++kk) {
      const int ci = kk * 4 + (l >> 4);
      bf16x8_t af[4], bq[4];
      #pragma unroll
      for (int m = 0; m < 4; ++m) {
        const int r = wr * 64 + m * 16 + (l & 15);
        af[m] = As[r * 8 + (ci ^ (r & 7))];
      }
      #pragma unroll
      for (int n = 0; n < 4; ++n) {
        const int r = wc * 64 + n * 16 + (l & 15);
        bq[n] = Bs[r * 8 + (ci ^ (r & 7))];
      }
      #pragma unroll
      for (int m = 0; m < 4; ++m)
        #pragma unroll
        for (int n = 0; n < 4; ++n)
          acc[m][n] = __builtin_amdgcn_mfma_f32_16x16x32_bf16(af[m], bq[n], acc[m][n], 0, 0, 0);
    }
    __syncthreads();
  }

  #pragma unroll
  for (int m = 0; m < 4; ++m)
    #pragma unroll
    for (int n = 0; n < 4; ++n)
      #pragma unroll
      for (int r = 0; r < 4; ++r) {
        const int rl_ = wr * 64 + m * 16 + (l >> 4) * 4 + r;
        const int cl_ = wc * 64 + n * 16 + (l & 15);
        float add = 0.f;
        #pragma unroll
        for (int j = 0; j < NJ; ++j)
          add += Lsh[rl_ * NJ + j] * Fsh[j * 128 + cl_];
        out[(size_t)(rtile * 128 + rl_) * DD + ct * 128 + cl_] = acc[m][n][r] + add;
      }
}

extern "C" void kernel_launch(void* const* d_in, const int* in_sizes, int n_in,
                              void* d_out, int out_size, void* d_ws, size_t ws_size,
                              hipStream_t stream) {
  const float* data = (const float*)d_in[0];
  const float* W1 = (const float*)d_in[1];
  const float* b1 = (const float*)d_in[2];
  const float* W2 = (const float*)d_in[3];
  float* out = (float*)d_out;

  char* ws = (char*)d_ws;
  unsigned short* Abuf = (unsigned short*)(ws + 0);          // 33554432 B
  unsigned short* W2T = (unsigned short*)(ws + 33554432);    //  2097152 B
  float* partial = (float*)(ws + 35651584);                  //  2097152 B
  float* scale = (float*)(ws + 37748736);                    //    65536 B
  float* cbuf = (float*)(ws + 37814272);                     //    65536 B
  float* mm = (float*)(ws + 37879808);                       //      512 B
  float* nd = (float*)(ws + 37880320);                       //      256 B
  float* S = (float*)(ws + 37880576);                        //    32768 B
  float* F = (float*)(ws + 37913344);                        //    32768 B
  float* Fpart = (float*)(ws + 37946112);                    //  2097152 B

  hipLaunchKernelGGL(k0_w2t, dim3(32, 32), dim3(256), 0, stream, W2, W2T);
  hipLaunchKernelGGL(k1_norm, dim3(MTOT), dim3(256), 0, stream, data, Abuf, scale);
  hipLaunchKernelGGL(k2_sim, dim3(BB * NTRI), dim3(256), 0, stream, Abuf, scale, partial);
  hipLaunchKernelGGL(k3a_counter, dim3(MTOT / 256), dim3(256), 0, stream, partial, scale, cbuf, mm);
  hipLaunchKernelGGL(k3b_nodes, dim3(1), dim3(64), 0, stream, mm, nd);
  hipLaunchKernelGGL(k3c_softS, dim3(NJ * DD / 256), dim3(256), 0, stream, nd, W1, b1, S);
  hipLaunchKernelGGL(k3d_Fpart, dim3(64), dim3(256), 0, stream, S, W2, Fpart);
  hipLaunchKernelGGL(k3e_Fred, dim3(NJ * DD / 256), dim3(256), 0, stream, Fpart, F);
  hipLaunchKernelGGL(k4_out, dim3(MTOT / 128 * (DD / 128)), dim3(256), 0, stream,
                     Abuf, W2T, cbuf, nd, F, out);
}

// Round 5
// 134.295 us; speedup vs baseline: 1.9854x; 1.3452x over previous
//
#include <hip/hip_runtime.h>
#include <hip/hip_bf16.h>
#include <math.h>

#define BB 8
#define NN 2048
#define DD 1024
#define MTOT (BB * NN)
#define NT (NN / 128)            // 16 row/col tiles per batch
#define NTRI (NT * (NT + 1) / 2) // 136 triangular tiles
#define NJ 8                     // interpolation nodes
#define PAD 12                   // padded j-stride (16B-aligned, conflict-free b128)

typedef __attribute__((ext_vector_type(8))) short bf16x8_t;
typedef __attribute__((ext_vector_type(4))) float f32x4_t;

__device__ __forceinline__ unsigned short f2bf(float f) {
  unsigned int u = __float_as_uint(f);
  unsigned int r = (u + 0x7FFFu + ((u >> 16) & 1u)) >> 16;
  return (unsigned short)r;
}

__device__ __forceinline__ void gload_lds16(const void* g, void* lds) {
  __builtin_amdgcn_global_load_lds(
      (const __attribute__((address_space(1))) void*)g,
      (__attribute__((address_space(3))) void*)lds, 16, 0, 0);
}

__device__ __forceinline__ float softplusf(float x) {
  return (x > 20.f) ? x : log1pf(expf(x));
}

// K0: W2 top half [1024,1024] f32 -> W2T [1024,1024] bf16 (W2T[n][k] = W2[k][n])
__global__ void k0_w2t(const float* __restrict__ W2, unsigned short* __restrict__ W2T) {
  __shared__ float tile[32][33];
  const int nb = blockIdx.x * 32;
  const int kb = blockIdx.y * 32;
  const int tx = threadIdx.x & 31, ty = threadIdx.x >> 5;
  #pragma unroll
  for (int i = 0; i < 32; i += 8)
    tile[ty + i][tx] = W2[(size_t)(kb + ty + i) * DD + nb + tx];
  __syncthreads();
  #pragma unroll
  for (int i = 0; i < 32; i += 8)
    W2T[(size_t)(nb + ty + i) * DD + kb + tx] = f2bf(tile[tx][ty + i]);
}

// K1: per-row sumsq -> scale; data f32 -> bf16 into Abuf [16384,1024]
__global__ void k1_norm(const float* __restrict__ data, unsigned short* __restrict__ Abuf,
                        float* __restrict__ scale) {
  const int row = blockIdx.x;
  const int t = threadIdx.x;
  float4 v = ((const float4*)(data + (size_t)row * DD))[t];
  float ss = v.x * v.x + v.y * v.y + v.z * v.z + v.w * v.w;
  #pragma unroll
  for (int i = 1; i < 64; i <<= 1) ss += __shfl_xor(ss, i);
  __shared__ float red[4];
  if ((t & 63) == 0) red[t >> 6] = ss;
  __syncthreads();
  if (t == 0) {
    float tot = red[0] + red[1] + red[2] + red[3];
    scale[row] = rsqrtf(fmaxf(tot, 1e-12f));
  }
  ushort4 o = make_ushort4(f2bf(v.x), f2bf(v.y), f2bf(v.z), f2bf(v.w));
  *(ushort4*)(&Abuf[(size_t)row * DD + t * 4]) = o;
}

// K2: triangular blocks rt<=ct of G = X@X^T per batch (X = bf16 data rows).
// Off-diagonal blocks emit row-side AND col-side weighted partials (relu(G) symmetric).
// partial[row][slot]: row-side -> slot ct*2+wc ; col-side -> slot rt*2+wr.
__launch_bounds__(256)
__global__ void k2_sim(const unsigned short* __restrict__ Abuf,
                       const float* __restrict__ scale,
                       float* __restrict__ partial) {
  __shared__ short As_s[128 * 64];
  __shared__ short Bs_s[128 * 64];
  const int t = threadIdx.x;
  const int w = t >> 6, l = t & 63;
  const int wr = w >> 1, wc = w & 1;

  const int nwg = BB * NTRI;  // 1088, %8==0
  const int logical = (blockIdx.x % 8) * (nwg / 8) + blockIdx.x / 8;
  const int b = logical / NTRI;
  int p = logical % NTRI;
  int rt = 0;
  while (p >= NT - rt) { p -= NT - rt; ++rt; }
  const int ct = rt + p;

  const size_t bbase = (size_t)b * NN * DD;
  const unsigned short* Ag = Abuf + bbase + (size_t)rt * 128 * DD;
  const unsigned short* Bg = Abuf + bbase + (size_t)ct * 128 * DD;
  const int lr = l >> 3;
  const int cg = (l & 7) ^ lr;  // swizzled global 16B-chunk
  f32x4_t acc[4][4] = {};

  for (int ks = 0; ks < DD / 64; ++ks) {
    #pragma unroll
    for (int i = 0; i < 4; ++i) {
      const int rl = i * 32 + w * 8 + lr;
      gload_lds16(Ag + (size_t)rl * DD + ks * 64 + cg * 8, &As_s[(i * 32 + w * 8) * 64]);
      gload_lds16(Bg + (size_t)rl * DD + ks * 64 + cg * 8, &Bs_s[(i * 32 + w * 8) * 64]);
    }
    __syncthreads();
    const bf16x8_t* As = (const bf16x8_t*)As_s;
    const bf16x8_t* Bs = (const bf16x8_t*)Bs_s;
    #pragma unroll
    for (int kk = 0; kk < 2; ++kk) {
      const int ci = kk * 4 + (l >> 4);
      bf16x8_t af[4], bq[4];
      #pragma unroll
      for (int m = 0; m < 4; ++m) {
        const int r = wr * 64 + m * 16 + (l & 15);
        af[m] = As[r * 8 + (ci ^ (r & 7))];
      }
      #pragma unroll
      for (int n = 0; n < 4; ++n) {
        const int r = wc * 64 + n * 16 + (l & 15);
        bq[n] = Bs[r * 8 + (ci ^ (r & 7))];
      }
      #pragma unroll
      for (int m = 0; m < 4; ++m)
        #pragma unroll
        for (int n = 0; n < 4; ++n)
          acc[m][n] = __builtin_amdgcn_mfma_f32_16x16x32_bf16(af[m], bq[n], acc[m][n], 0, 0, 0);
    }
    __syncthreads();
  }

  const float* sb = scale + (size_t)b * NN;

  {  // row-side
    float scol[4];
    #pragma unroll
    for (int n = 0; n < 4; ++n)
      scol[n] = sb[ct * 128 + wc * 64 + n * 16 + (l & 15)];
    #pragma unroll
    for (int m = 0; m < 4; ++m) {
      #pragma unroll
      for (int r = 0; r < 4; ++r) {
        float x = 0.f;
        #pragma unroll
        for (int n = 0; n < 4; ++n)
          x += scol[n] * fmaxf(acc[m][n][r], 0.f);
        #pragma unroll
        for (int off = 1; off < 16; off <<= 1)
          x += __shfl_xor(x, off);
        if ((l & 15) == 0) {
          const int row = rt * 128 + wr * 64 + m * 16 + (l >> 4) * 4 + r;
          partial[((size_t)(b * NN + row)) * 32 + ct * 2 + wc] = x;
        }
      }
    }
  }

  if (rt != ct) {  // col-side
    float srow[4][4];
    #pragma unroll
    for (int m = 0; m < 4; ++m)
      #pragma unroll
      for (int r = 0; r < 4; ++r)
        srow[m][r] = sb[rt * 128 + wr * 64 + m * 16 + (l >> 4) * 4 + r];
    #pragma unroll
    for (int n = 0; n < 4; ++n) {
      float y = 0.f;
      #pragma unroll
      for (int m = 0; m < 4; ++m)
        #pragma unroll
        for (int r = 0; r < 4; ++r)
          y += srow[m][r] * fmaxf(acc[m][n][r], 0.f);
      y += __shfl_xor(y, 16);
      y += __shfl_xor(y, 32);
      if (l < 16) {
        const int crow = ct * 128 + wc * 64 + n * 16 + l;
        partial[((size_t)(b * NN + crow)) * 32 + rt * 2 + wr] = y;
      }
    }
  }
}

// K3a: c[row] = scale[row]*sum(partial[row][0..32)); per-block min/max -> mm[64][2]
__global__ void k3a_counter(const float* __restrict__ partial, const float* __restrict__ scale,
                            float* __restrict__ cbuf, float* __restrict__ mm) {
  const int row = blockIdx.x * 256 + threadIdx.x;
  const float4* pr = (const float4*)(partial + (size_t)row * 32);
  float c = 0.f;
  #pragma unroll
  for (int i = 0; i < 8; ++i) { float4 v = pr[i]; c += v.x + v.y + v.z + v.w; }
  c *= scale[row];
  cbuf[row] = c;
  float mn = c, mx = c;
  #pragma unroll
  for (int i = 1; i < 64; i <<= 1) {
    mn = fminf(mn, __shfl_xor(mn, i));
    mx = fmaxf(mx, __shfl_xor(mx, i));
  }
  __shared__ float smn[4], smx[4];
  if ((threadIdx.x & 63) == 0) { smn[threadIdx.x >> 6] = mn; smx[threadIdx.x >> 6] = mx; }
  __syncthreads();
  if (threadIdx.x == 0) {
    mn = fminf(fminf(smn[0], smn[1]), fminf(smn[2], smn[3]));
    mx = fmaxf(fmaxf(smx[0], smx[1]), fmaxf(smx[2], smx[3]));
    mm[blockIdx.x * 2] = mn;
    mm[blockIdx.x * 2 + 1] = mx;
  }
}

// K3b: reduce min/max over 64 blocks; compute 8 Chebyshev nodes + barycentric invD
__global__ void k3b_nodes(const float* __restrict__ mm, float* __restrict__ nd) {
  const int t = threadIdx.x;  // 64
  float mn = mm[t * 2], mx = mm[t * 2 + 1];
  #pragma unroll
  for (int i = 1; i < 64; i <<= 1) {
    mn = fminf(mn, __shfl_xor(mn, i));
    mx = fmaxf(mx, __shfl_xor(mx, i));
  }
  if (t == 0) {
    float mid = 0.5f * (mn + mx);
    float rad = 0.5f * (mx - mn);
    rad = fmaxf(rad, fmaxf(1e-3f, 1e-3f * fabsf(mid)));
    float c[NJ];
    #pragma unroll
    for (int j = 0; j < NJ; ++j)
      c[j] = mid + rad * cosf(3.14159265358979f * (2 * j + 1) / (2.0f * NJ));
    #pragma unroll
    for (int j = 0; j < NJ; ++j) nd[j] = c[j];
    #pragma unroll
    for (int j = 0; j < NJ; ++j) {
      float d = 1.f;
      #pragma unroll
      for (int i = 0; i < NJ; ++i)
        if (i != j) d *= (c[j] - c[i]);
      nd[NJ + j] = 1.f / d;
    }
  }
}

// K3c: S[j][d] = softplus(c_j*W1[d] + b1[d])
__global__ void k3c_softS(const float* __restrict__ nd, const float* __restrict__ W1,
                          const float* __restrict__ b1, float* __restrict__ S) {
  const int gid = blockIdx.x * 256 + threadIdx.x;  // 8192
  const int j = gid >> 10, d = gid & 1023;
  S[gid] = softplusf(nd[j] * W1[d] + b1[d]);
}

// K3d: Fpart[s][j][n] = sum_{d in slice s} S[j][d]*W2[(1024+d)][n]  (64 slices of 16)
__global__ void k3d_Fpart(const float* __restrict__ S, const float* __restrict__ W2,
                          float* __restrict__ Fpart) {
  const int s = blockIdx.x;   // 64
  const int t = threadIdx.x;  // 256 -> float4 over n
  float4 acc[NJ] = {};
  for (int dd = 0; dd < 16; ++dd) {
    const int d = s * 16 + dd;
    float4 wv = ((const float4*)(W2 + (size_t)(DD + d) * DD))[t];
    #pragma unroll
    for (int j = 0; j < NJ; ++j) {
      float sv = S[j * DD + d];
      acc[j].x += sv * wv.x; acc[j].y += sv * wv.y;
      acc[j].z += sv * wv.z; acc[j].w += sv * wv.w;
    }
  }
  #pragma unroll
  for (int j = 0; j < NJ; ++j)
    ((float4*)(Fpart + ((size_t)s * NJ + j) * DD))[t] = acc[j];
}

// K3e: F[j][n] = sum_s Fpart[s][j][n]
__global__ void k3e_Fred(const float* __restrict__ Fpart, float* __restrict__ F) {
  const int gid = blockIdx.x * 256 + threadIdx.x;  // 8192
  float a = 0.f;
  for (int s = 0; s < 64; ++s) a += Fpart[((size_t)s * NJ) * DD + gid];
  F[gid] = a;
}

// K3f: LmatT[j][row] = invD_j * prod_{i!=j} (c[row] - nd[i])   (barycentric Lagrange)
__global__ void k3f_Lmat(const float* __restrict__ cbuf, const float* __restrict__ nd,
                         float* __restrict__ LmatT) {
  const int row = blockIdx.x * 256 + threadIdx.x;
  const float c = cbuf[row];
  float ndv[NJ], inv[NJ];
  #pragma unroll
  for (int j = 0; j < NJ; ++j) { ndv[j] = nd[j]; inv[j] = nd[NJ + j]; }
  #pragma unroll
  for (int j = 0; j < NJ; ++j) {
    float prod = inv[j];
    #pragma unroll
    for (int i = 0; i < NJ; ++i)
      if (i != j) prod *= (c - ndv[i]);
    LmatT[(size_t)j * MTOT + row] = prod;
  }
}

// K4: out[16384,1024] f32 = Abuf[16384,1024]bf16 @ W2T^T  +  Lmat[row,:] @ F  (rank-8)
__launch_bounds__(256)
__global__ void k4_out(const unsigned short* __restrict__ Abuf,
                       const unsigned short* __restrict__ W2T,
                       const float* __restrict__ LmatT,
                       const float* __restrict__ F,
                       float* __restrict__ out) {
  __shared__ short As_s[128 * 64];
  __shared__ short Bs_s[128 * 64];
  __shared__ float Fsh[128 * PAD];  // [col 128][j 8, pad 12]
  __shared__ float Lsh[128 * PAD];  // [row 128][j 8, pad 12]
  const int t = threadIdx.x;
  const int w = t >> 6, l = t & 63;
  const int wr = w >> 1, wc = w & 1;

  // XCD-aware: each XCD gets 16 consecutive rtiles x all 8 cts (nwg=1024)
  const int logical = (blockIdx.x % 8) * 128 + blockIdx.x / 8;
  const int rtile = logical >> 3;
  const int ct = logical & 7;

  const unsigned short* Ag = Abuf + (size_t)rtile * 128 * DD;
  const unsigned short* Bg = W2T + (size_t)ct * 128 * DD;
  const int lr = l >> 3;
  const int cg = (l & 7) ^ lr;
  f32x4_t acc[4][4] = {};

  // stage F slice + precomputed L rows (coalesced global reads; first K-loop
  // barrier orders these LDS writes against epilogue reads)
  #pragma unroll
  for (int q = 0; q < 4; ++q) {
    const int idx = q * 256 + t;  // 1024 = 8j x 128
    const int j = idx >> 7, n = idx & 127;
    Fsh[n * PAD + j] = F[j * DD + ct * 128 + n];
    Lsh[n * PAD + j] = LmatT[(size_t)j * MTOT + rtile * 128 + n];
  }

  for (int ks = 0; ks < DD / 64; ++ks) {
    #pragma unroll
    for (int i = 0; i < 4; ++i) {
      const int rl = i * 32 + w * 8 + lr;
      gload_lds16(Ag + (size_t)rl * DD + ks * 64 + cg * 8, &As_s[(i * 32 + w * 8) * 64]);
      gload_lds16(Bg + (size_t)rl * DD + ks * 64 + cg * 8, &Bs_s[(i * 32 + w * 8) * 64]);
    }
    __syncthreads();
    const bf16x8_t* As = (const bf16x8_t*)As_s;
    const bf16x8_t* Bs = (const bf16x8_t*)Bs_s;
    #pragma unroll
    for (int kk = 0; kk < 2; ++kk) {
      const int ci = kk * 4 + (l >> 4);
      bf16x8_t af[4], bq[4];
      #pragma unroll
      for (int m = 0; m < 4; ++m) {
        const int r = wr * 64 + m * 16 + (l & 15);
        af[m] = As[r * 8 + (ci ^ (r & 7))];
      }
      #pragma unroll
      for (int n = 0; n < 4; ++n) {
        const int r = wc * 64 + n * 16 + (l & 15);
        bq[n] = Bs[r * 8 + (ci ^ (r & 7))];
      }
      #pragma unroll
      for (int m = 0; m < 4; ++m)
        #pragma unroll
        for (int n = 0; n < 4; ++n)
          acc[m][n] = __builtin_amdgcn_mfma_f32_16x16x32_bf16(af[m], bq[n], acc[m][n], 0, 0, 0);
    }
    __syncthreads();
  }

  #pragma unroll
  for (int m = 0; m < 4; ++m)
    #pragma unroll
    for (int r = 0; r < 4; ++r) {
      const int rl_ = wr * 64 + m * 16 + (l >> 4) * 4 + r;
      const f32x4_t L0 = *(const f32x4_t*)&Lsh[rl_ * PAD];
      const f32x4_t L1 = *(const f32x4_t*)&Lsh[rl_ * PAD + 4];
      #pragma unroll
      for (int n = 0; n < 4; ++n) {
        const int cl_ = wc * 64 + n * 16 + (l & 15);
        const f32x4_t F0 = *(const f32x4_t*)&Fsh[cl_ * PAD];
        const f32x4_t F1 = *(const f32x4_t*)&Fsh[cl_ * PAD + 4];
        const float add = L0[0] * F0[0] + L0[1] * F0[1] + L0[2] * F0[2] + L0[3] * F0[3] +
                          L1[0] * F1[0] + L1[1] * F1[1] + L1[2] * F1[2] + L1[3] * F1[3];
        out[(size_t)(rtile * 128 + rl_) * DD + ct * 128 + cl_] = acc[m][n][r] + add;
      }
    }
}

extern "C" void kernel_launch(void* const* d_in, const int* in_sizes, int n_in,
                              void* d_out, int out_size, void* d_ws, size_t ws_size,
                              hipStream_t stream) {
  const float* data = (const float*)d_in[0];
  const float* W1 = (const float*)d_in[1];
  const float* b1 = (const float*)d_in[2];
  const float* W2 = (const float*)d_in[3];
  float* out = (float*)d_out;

  char* ws = (char*)d_ws;
  unsigned short* Abuf = (unsigned short*)(ws + 0);          // 33554432 B
  unsigned short* W2T = (unsigned short*)(ws + 33554432);    //  2097152 B
  float* partial = (float*)(ws + 35651584);                  //  2097152 B
  float* scale = (float*)(ws + 37748736);                    //    65536 B
  float* cbuf = (float*)(ws + 37814272);                     //    65536 B
  float* mm = (float*)(ws + 37879808);                       //      512 B
  float* nd = (float*)(ws + 37880320);                       //      256 B
  float* S = (float*)(ws + 37880576);                        //    32768 B
  float* F = (float*)(ws + 37913344);                        //    32768 B
  float* Fpart = (float*)(ws + 37946112);                    //  2097152 B
  float* LmatT = (float*)(ws + 40043264);                    //   524288 B

  hipLaunchKernelGGL(k0_w2t, dim3(32, 32), dim3(256), 0, stream, W2, W2T);
  hipLaunchKernelGGL(k1_norm, dim3(MTOT), dim3(256), 0, stream, data, Abuf, scale);
  hipLaunchKernelGGL(k2_sim, dim3(BB * NTRI), dim3(256), 0, stream, Abuf, scale, partial);
  hipLaunchKernelGGL(k3a_counter, dim3(MTOT / 256), dim3(256), 0, stream, partial, scale, cbuf, mm);
  hipLaunchKernelGGL(k3b_nodes, dim3(1), dim3(64), 0, stream, mm, nd);
  hipLaunchKernelGGL(k3c_softS, dim3(NJ * DD / 256), dim3(256), 0, stream, nd, W1, b1, S);
  hipLaunchKernelGGL(k3d_Fpart, dim3(64), dim3(256), 0, stream, S, W2, Fpart);
  hipLaunchKernelGGL(k3e_Fred, dim3(NJ * DD / 256), dim3(256), 0, stream, Fpart, F);
  hipLaunchKernelGGL(k3f_Lmat, dim3(MTOT / 256), dim3(256), 0, stream, cbuf, nd, LmatT);
  hipLaunchKernelGGL(k4_out, dim3(MTOT / 128 * (DD / 128)), dim3(256), 0, stream,
                     Abuf, W2T, LmatT, F, out);
}